// Round 2
// baseline (1717.783 us; speedup 1.0000x reference)
//
#include <hip/hip_runtime.h>

// Problem constants (fixed by the reference).
static constexpr int N_ = 1024;
static constexpr int S_ = 144;
static constexpr int R_ = 96;
static constexpr int K_ = 128;
static constexpr int D_ = 768;

// ---------------------------------------------------------------------------
// Kernel 1: ragged lambdas -> dense (R,K) with 0 padding.
// ---------------------------------------------------------------------------
__global__ __launch_bounds__(256) void k_pad_lambdas(
    const float* __restrict__ lambdas, const int* __restrict__ lens,
    float* __restrict__ ul) {
  __shared__ int offs[R_];
  if (threadIdx.x == 0) {
    int acc = 0;
    for (int r = 0; r < R_; ++r) { offs[r] = acc; acc += lens[r]; }
  }
  __syncthreads();
  for (int i = threadIdx.x; i < R_ * K_; i += 256) {
    int r = i >> 7;          // / K_ (K_=128)
    int k = i & (K_ - 1);
    float v = 0.0f;
    if (k < lens[r]) v = lambdas[offs[r] + k];
    ul[i] = v;
  }
}

// ---------------------------------------------------------------------------
// Kernel 2: out[n,d] = sum over ablated indices of x[n,idx,d]  (initializes out)
// ---------------------------------------------------------------------------
__global__ __launch_bounds__(256) void k_ablated(
    const float* __restrict__ x, const int* __restrict__ abl,
    float* __restrict__ out, int nab) {
  int i = blockIdx.x * 256 + threadIdx.x;
  const int nd4 = N_ * D_ / 4;
  if (i >= nd4) return;
  int n = i / (D_ / 4);
  int d4 = i - n * (D_ / 4);
  const float4* xr = (const float4*)x;
  size_t base = (size_t)n * (S_ * D_ / 4) + d4;
  float4 acc = make_float4(0.f, 0.f, 0.f, 0.f);
  for (int j = 0; j < nab; ++j) {
    float4 v = xr[base + (size_t)abl[j] * (D_ / 4)];
    acc.x += v.x; acc.y += v.y; acc.z += v.z; acc.w += v.w;
  }
  ((float4*)out)[i] = acc;
}

// ---------------------------------------------------------------------------
// Kernel 3 (pass 1): per r, coeffs[n, rz*K + k] =
//     ul[r,k] * sum_d (x[n,res_r,d]-means[r,d]) * bases[r,k,d]
// NT GEMM, 64x64 tile, 32-wide D chunks, 4x4 per thread.
// ---------------------------------------------------------------------------
__global__ __launch_bounds__(256) void k_pass1(
    const float* __restrict__ x, const float* __restrict__ bases,
    const float* __restrict__ means, const int* __restrict__ resi,
    const float* __restrict__ ul, float* __restrict__ coeffs,
    int r0, int Rc) {
  const int rz = blockIdx.z;
  const int r  = r0 + rz;
  const int n0 = blockIdx.x * 64;
  const int k0 = blockIdx.y * 64;
  const int s  = resi[r];

  __shared__ float As[64][33];
  __shared__ float Bs[64][33];

  const int t  = threadIdx.x;
  const int tx = t & 15, ty = t >> 4;
  const int lc = (t & 7) * 4;   // 0,4,...,28 (float col within 32-chunk)
  const int lr = t >> 3;        // 0..31

  const float* xbase = x + (size_t)s * D_;
  const float* bbase = bases + ((size_t)r * K_ + k0) * D_;
  const float* mbase = means + (size_t)r * D_;

  float acc[4][4] = {};

  for (int d0 = 0; d0 < D_; d0 += 32) {
    float4 mv = *(const float4*)(mbase + d0 + lc);
#pragma unroll
    for (int rr = 0; rr < 2; ++rr) {
      int row = lr + rr * 32;
      float4 xv = *(const float4*)(xbase + (size_t)(n0 + row) * (S_ * D_) + d0 + lc);
      As[row][lc + 0] = xv.x - mv.x;
      As[row][lc + 1] = xv.y - mv.y;
      As[row][lc + 2] = xv.z - mv.z;
      As[row][lc + 3] = xv.w - mv.w;
      float4 bv = *(const float4*)(bbase + (size_t)row * D_ + d0 + lc);
      Bs[row][lc + 0] = bv.x;
      Bs[row][lc + 1] = bv.y;
      Bs[row][lc + 2] = bv.z;
      Bs[row][lc + 3] = bv.w;
    }
    __syncthreads();
#pragma unroll
    for (int dd = 0; dd < 32; ++dd) {
      float a[4], b[4];
#pragma unroll
      for (int i = 0; i < 4; ++i) a[i] = As[ty * 4 + i][dd];
#pragma unroll
      for (int j = 0; j < 4; ++j) b[j] = Bs[tx * 4 + j][dd];
#pragma unroll
      for (int i = 0; i < 4; ++i)
#pragma unroll
        for (int j = 0; j < 4; ++j)
          acc[i][j] = fmaf(a[i], b[j], acc[i][j]);
    }
    __syncthreads();
  }

  const int ldc = Rc * K_;
#pragma unroll
  for (int i = 0; i < 4; ++i) {
    int n = n0 + ty * 4 + i;
#pragma unroll
    for (int j = 0; j < 4; ++j) {
      int k = k0 + tx * 4 + j;
      coeffs[(size_t)n * ldc + rz * K_ + k] = ul[r * K_ + k] * acc[i][j];
    }
  }
}

// ---------------------------------------------------------------------------
// Kernel 4 (pass 2): out(N,D) += coeffs(N,Kg) @ invb(Kg,D)
// NN GEMM, 64x64 tile, 32-deep chunks, 4x4 per thread. "+=" epilogue so
// chunked launches accumulate correctly.
// ---------------------------------------------------------------------------
__global__ __launch_bounds__(256) void k_pass2(
    const float* __restrict__ coeffs, const float* __restrict__ invb,
    float* __restrict__ out, int Kg) {
  const int n0 = blockIdx.x * 64;
  const int d0 = blockIdx.y * 64;

  __shared__ float As[64][33];
  __shared__ float Bs[32][65];

  const int t  = threadIdx.x;
  const int tx = t & 15, ty = t >> 4;
  const int lca = (t & 7) * 4;    // 0..28
  const int lra = t >> 3;         // 0..31
  const int lcb = (t & 15) * 4;   // 0..60
  const int lrb = t >> 4;         // 0..15

  float acc[4][4] = {};

  for (int kk0 = 0; kk0 < Kg; kk0 += 32) {
#pragma unroll
    for (int rr = 0; rr < 2; ++rr) {
      int row = lra + rr * 32;
      float4 av = *(const float4*)(coeffs + (size_t)(n0 + row) * Kg + kk0 + lca);
      As[row][lca + 0] = av.x;
      As[row][lca + 1] = av.y;
      As[row][lca + 2] = av.z;
      As[row][lca + 3] = av.w;
      int brow = lrb + rr * 16;
      float4 bv = *(const float4*)(invb + (size_t)(kk0 + brow) * D_ + d0 + lcb);
      Bs[brow][lcb + 0] = bv.x;
      Bs[brow][lcb + 1] = bv.y;
      Bs[brow][lcb + 2] = bv.z;
      Bs[brow][lcb + 3] = bv.w;
    }
    __syncthreads();
#pragma unroll
    for (int kk = 0; kk < 32; ++kk) {
      float a[4], b[4];
#pragma unroll
      for (int i = 0; i < 4; ++i) a[i] = As[ty * 4 + i][kk];
#pragma unroll
      for (int j = 0; j < 4; ++j) b[j] = Bs[kk][tx * 4 + j];
#pragma unroll
      for (int i = 0; i < 4; ++i)
#pragma unroll
        for (int j = 0; j < 4; ++j)
          acc[i][j] = fmaf(a[i], b[j], acc[i][j]);
    }
    __syncthreads();
  }

#pragma unroll
  for (int i = 0; i < 4; ++i) {
    int n = n0 + ty * 4 + i;
#pragma unroll
    for (int j = 0; j < 4; ++j) {
      int d = d0 + tx * 4 + j;
      out[(size_t)n * D_ + d] += acc[i][j];
    }
  }
}

// ---------------------------------------------------------------------------
// Fallback (only if ws_size can't hold even a 1-r coeffs chunk): fused
// per-(n-tile, r) block. Stage A: coeffs 64x128 into LDS. Stage B:
// coeffs @ invb_r, atomicAdd into out. Needs ZERO workspace.
// ---------------------------------------------------------------------------
__global__ __launch_bounds__(256) void k_fused(
    const float* __restrict__ x, const float* __restrict__ bases,
    const float* __restrict__ invb, const float* __restrict__ means,
    const int* __restrict__ resi, const float* __restrict__ lambdas,
    const int* __restrict__ lens, float* __restrict__ out) {
  const int r  = blockIdx.y;
  const int n0 = blockIdx.x * 64;
  const int s  = resi[r];

  __shared__ float As[64][33];    // x-mu chunk (also reused for invb stage B)
  __shared__ float Bs[128][33];   // bases chunk / invb chunk
  __shared__ float Cs[64][132];   // lambda-scaled coeffs
  __shared__ float lam[K_];
  __shared__ int offS;

  const int t  = threadIdx.x;
  if (t == 0) {
    int o = 0;
    for (int i = 0; i < r; ++i) o += lens[i];
    offS = o;
  }
  __syncthreads();
  if (t < K_) lam[t] = (t < lens[r]) ? lambdas[offS + t] : 0.0f;

  const int lc = (t & 7) * 4;  // 0..28
  const int lr = t >> 3;       // 0..31
  const float* mbase = means + (size_t)r * D_;
  const float* bbase = bases + (size_t)r * K_ * D_;

  // Stage A: acc[4][8] -> 64 rows (n) x 128 cols (k)
  const int tx = t & 15, ty = t >> 4;
  float acc[4][8] = {};
  for (int d0 = 0; d0 < D_; d0 += 32) {
    float4 mv = *(const float4*)(mbase + d0 + lc);
#pragma unroll
    for (int rr = 0; rr < 2; ++rr) {
      int row = lr + rr * 32;
      float4 xv = *(const float4*)(x + ((size_t)(n0 + row) * S_ + s) * D_ + d0 + lc);
      As[row][lc + 0] = xv.x - mv.x;
      As[row][lc + 1] = xv.y - mv.y;
      As[row][lc + 2] = xv.z - mv.z;
      As[row][lc + 3] = xv.w - mv.w;
    }
#pragma unroll
    for (int rr = 0; rr < 4; ++rr) {
      int row = lr + rr * 32;
      float4 bv = *(const float4*)(bbase + (size_t)row * D_ + d0 + lc);
      Bs[row][lc + 0] = bv.x;
      Bs[row][lc + 1] = bv.y;
      Bs[row][lc + 2] = bv.z;
      Bs[row][lc + 3] = bv.w;
    }
    __syncthreads();
#pragma unroll
    for (int dd = 0; dd < 32; ++dd) {
      float a[4], b[8];
#pragma unroll
      for (int i = 0; i < 4; ++i) a[i] = As[ty * 4 + i][dd];
#pragma unroll
      for (int j = 0; j < 8; ++j) b[j] = Bs[tx * 8 + j][dd];
#pragma unroll
      for (int i = 0; i < 4; ++i)
#pragma unroll
        for (int j = 0; j < 8; ++j)
          acc[i][j] = fmaf(a[i], b[j], acc[i][j]);
    }
    __syncthreads();
  }
#pragma unroll
  for (int i = 0; i < 4; ++i)
#pragma unroll
    for (int j = 0; j < 8; ++j)
      Cs[ty * 4 + i][tx * 8 + j] = lam[tx * 8 + j] * acc[i][j];
  __syncthreads();

  // Stage B: loop d-chunks of 32; invb chunk into Bs; 4x2 outputs/thread.
  const float* ibase = invb + (size_t)r * K_ * D_;
  const int tx2 = t & 15;  // col group (2 cols)
  for (int d0 = 0; d0 < D_; d0 += 32) {
#pragma unroll
    for (int rr = 0; rr < 4; ++rr) {
      int row = lr + rr * 32;
      float4 bv = *(const float4*)(ibase + (size_t)row * D_ + d0 + lc);
      Bs[row][lc + 0] = bv.x;
      Bs[row][lc + 1] = bv.y;
      Bs[row][lc + 2] = bv.z;
      Bs[row][lc + 3] = bv.w;
    }
    __syncthreads();
    float c[4][2] = {};
#pragma unroll
    for (int k = 0; k < K_; ++k) {
      float a[4], b[2];
#pragma unroll
      for (int i = 0; i < 4; ++i) a[i] = Cs[ty * 4 + i][k];
#pragma unroll
      for (int j = 0; j < 2; ++j) b[j] = Bs[k][tx2 * 2 + j];
#pragma unroll
      for (int i = 0; i < 4; ++i)
#pragma unroll
        for (int j = 0; j < 2; ++j)
          c[i][j] = fmaf(a[i], b[j], c[i][j]);
    }
#pragma unroll
    for (int i = 0; i < 4; ++i)
#pragma unroll
      for (int j = 0; j < 2; ++j)
        atomicAdd(&out[(size_t)(n0 + ty * 4 + i) * D_ + d0 + tx2 * 2 + j], c[i][j]);
    __syncthreads();
  }
}

// ---------------------------------------------------------------------------
extern "C" void kernel_launch(void* const* d_in, const int* in_sizes, int n_in,
                              void* d_out, int out_size, void* d_ws, size_t ws_size,
                              hipStream_t stream) {
  const float* x       = (const float*)d_in[0];
  const float* lambdas = (const float*)d_in[1];
  const float* bases   = (const float*)d_in[2];
  const float* invb    = (const float*)d_in[3];
  const float* means   = (const float*)d_in[4];
  const int*   resi    = (const int*)d_in[5];   // JAX x64-disabled -> int32
  const int*   abl     = (const int*)d_in[6];   // int32
  const int*   lens    = (const int*)d_in[7];   // int32
  float* out = (float*)d_out;

  const int nab = in_sizes[6];  // number of ablated indices (48)

  // out initialized with the ablated-slice sum; both paths then accumulate.
  k_ablated<<<(N_ * D_ / 4 + 255) / 256, 256, 0, stream>>>(x, abl, out, nab);

  // Workspace layout: [ul: R*K floats][coeffs: N*Rc*K floats]
  const size_t ul_bytes = (size_t)R_ * K_ * sizeof(float);
  const size_t per_r = (size_t)N_ * K_ * sizeof(float);

  if (ws_size >= ul_bytes + per_r) {
    float* ul = (float*)d_ws;
    float* coeffs = (float*)((char*)d_ws + ul_bytes);
    int Rc = (int)((ws_size - ul_bytes) / per_r);
    if (Rc > R_) Rc = R_;

    k_pad_lambdas<<<1, 256, 0, stream>>>(lambdas, lens, ul);
    for (int r0 = 0; r0 < R_; r0 += Rc) {
      int rc = (R_ - r0 < Rc) ? (R_ - r0) : Rc;
      dim3 g1(N_ / 64, K_ / 64, rc);
      k_pass1<<<g1, 256, 0, stream>>>(x, bases, means, resi, ul, coeffs, r0, rc);
      dim3 g2(N_ / 64, D_ / 64);
      k_pass2<<<g2, 256, 0, stream>>>(coeffs, invb + (size_t)r0 * K_ * D_, out,
                                      rc * K_);
    }
  } else {
    dim3 g(N_ / 64, R_);
    k_fused<<<g, 256, 0, stream>>>(x, bases, invb, means, resi, lambdas, lens,
                                   out);
  }
}

// Round 4
// 749.119 us; speedup vs baseline: 2.2931x; 2.2931x over previous
//
#include <hip/hip_runtime.h>

// Problem constants (fixed by the reference).
static constexpr int N_ = 1024;
static constexpr int S_ = 144;
static constexpr int R_ = 96;
static constexpr int K_ = 128;
static constexpr int D_ = 768;

typedef __attribute__((ext_vector_type(8))) short short8;   // 8 bf16 = 4 VGPR
typedef __attribute__((ext_vector_type(4))) short short4_t; // 4 bf16 = 8 B
typedef __attribute__((ext_vector_type(4))) float floatx4;  // MFMA acc

__device__ inline short f2bf(float f) {  // fp32 -> bf16 RNE
  unsigned u = __builtin_bit_cast(unsigned, f);
  return (short)((u + 0x7FFFu + ((u >> 16) & 1u)) >> 16);
}

// ---------------------------------------------------------------------------
// ragged lambdas -> dense (R,K) fp32 with 0 padding.
// ---------------------------------------------------------------------------
__global__ __launch_bounds__(256) void k_pad_lambdas(
    const float* __restrict__ lambdas, const int* __restrict__ lens,
    float* __restrict__ ul) {
  __shared__ int offs[R_];
  if (threadIdx.x == 0) {
    int acc = 0;
    for (int r = 0; r < R_; ++r) { offs[r] = acc; acc += lens[r]; }
  }
  __syncthreads();
  for (int i = threadIdx.x; i < R_ * K_; i += 256) {
    int r = i >> 7;
    int k = i & (K_ - 1);
    float v = 0.0f;
    if (k < lens[r]) v = lambdas[offs[r] + k];
    ul[i] = v;
  }
}

// ---------------------------------------------------------------------------
// bbf[r][k][d] = bf16(bases[r][k][d] * ul[r][k])   (scale in fp32, round once)
// ---------------------------------------------------------------------------
__global__ __launch_bounds__(256) void k_cvt_bases(
    const float* __restrict__ bases, const float* __restrict__ ul,
    short* __restrict__ bbf) {
  size_t i = ((size_t)blockIdx.x * 256 + threadIdx.x) * 4;
  if (i >= (size_t)R_ * K_ * D_) return;
  int rk = (int)(i / D_);
  float s = ul[rk];
  float4 v = *(const float4*)(bases + i);
  short4_t o;
  o.x = f2bf(v.x * s); o.y = f2bf(v.y * s);
  o.z = f2bf(v.z * s); o.w = f2bf(v.w * s);
  *(short4_t*)(bbf + i) = o;
}

// ---------------------------------------------------------------------------
// ibt[d][r*K+k] = bf16(invb[r][k][d])   (32x32 LDS-tiled transpose per r)
// ---------------------------------------------------------------------------
__global__ __launch_bounds__(256) void k_trans_inv(
    const float* __restrict__ invb, short* __restrict__ ibt) {
  const int d0 = blockIdx.x * 32;
  const int k0 = blockIdx.y * 32;
  const int r  = blockIdx.z;
  __shared__ short tile[32][33];
  const int t = threadIdx.x;
  {
    int kr = t >> 3;          // 0..31
    int dg = (t & 7) * 4;     // 0..28
    float4 v = *(const float4*)(invb + ((size_t)r * K_ + k0 + kr) * D_ + d0 + dg);
    tile[kr][dg + 0] = f2bf(v.x);
    tile[kr][dg + 1] = f2bf(v.y);
    tile[kr][dg + 2] = f2bf(v.z);
    tile[kr][dg + 3] = f2bf(v.w);
  }
  __syncthreads();
  {
    int dr = t >> 3;          // 0..31
    int kg = (t & 7) * 4;     // 0..28
    short4_t o;
    o.x = tile[kg + 0][dr]; o.y = tile[kg + 1][dr];
    o.z = tile[kg + 2][dr]; o.w = tile[kg + 3][dr];
    *(short4_t*)(ibt + (size_t)(d0 + dr) * (R_ * K_) + r * K_ + k0 + kg) = o;
  }
}

// ---------------------------------------------------------------------------
// out[n,d] = sum over ablated indices of x[n,idx,d]  (initializes out)
// ---------------------------------------------------------------------------
__global__ __launch_bounds__(256) void k_ablated(
    const float* __restrict__ x, const int* __restrict__ abl,
    float* __restrict__ out, int nab) {
  int i = blockIdx.x * 256 + threadIdx.x;
  const int nd4 = N_ * D_ / 4;
  if (i >= nd4) return;
  int n = i / (D_ / 4);
  int d4 = i - n * (D_ / 4);
  const float4* xr = (const float4*)x;
  size_t base = (size_t)n * (S_ * D_ / 4) + d4;
  float4 acc = make_float4(0.f, 0.f, 0.f, 0.f);
  for (int j = 0; j < nab; ++j) {
    float4 v = xr[base + (size_t)abl[j] * (D_ / 4)];
    acc.x += v.x; acc.y += v.y; acc.z += v.z; acc.w += v.w;
  }
  ((float4*)out)[i] = acc;
}

// ---------------------------------------------------------------------------
// Pass 1 (MFMA): per (n-tile 128, r):
//   coeffs_bf16[n][r*128+k] = sum_d bf16(x[n,s_r,d]-mu) * bbf[r][k][d]
// 128x128 tile, BK=64, 4 waves each computing a 64x64 quadrant via 4x4
// mfma_f32_16x16x32_bf16. LDS rows padded to 72 shorts.
// Staging coverage (round-3 bugfix): full 128 rows x 64 shorts per tile:
//   256 threads x 4 rounds x 8 shorts = 8192 shorts.
// ---------------------------------------------------------------------------
__global__ __launch_bounds__(256) void k1_mfma(
    const float* __restrict__ x, const short* __restrict__ bbf,
    const float* __restrict__ means, const int* __restrict__ resi,
    short* __restrict__ coeffs) {
  const int r  = blockIdx.y;
  const int n0 = blockIdx.x * 128;
  const int s  = resi[r];

  __shared__ short As[128][72];
  __shared__ short Bs[128][72];

  const int t = threadIdx.x;
  const int wid = t >> 6, l = t & 63;
  const int wr = wid >> 1, wc = wid & 1;
  const int lm = l & 15, quad = l >> 4;

  floatx4 acc[4][4];
#pragma unroll
  for (int i = 0; i < 4; ++i)
#pragma unroll
    for (int j = 0; j < 4; ++j) acc[i][j] = (floatx4)(0.0f);

  const int arow = t >> 4;         // 0..15 (x staging row within round)
  const int acol = (t & 15) * 4;   // 0..60 (floats)
  const int brow = t >> 3;         // 0..31 (bbf staging row within round)
  const int bcol = (t & 7) * 8;    // 0..56 shorts (16 B)

  const float* xb = x + (size_t)s * D_;
  const short* bb = bbf + (size_t)r * K_ * D_;
  const float* mb = means + (size_t)r * D_;

  for (int d0 = 0; d0 < D_; d0 += 64) {
    float4 mv = *(const float4*)(mb + d0 + acol);
#pragma unroll
    for (int rr = 0; rr < 8; ++rr) {
      int row = arow + rr * 16;
      float4 xv = *(const float4*)(xb + (size_t)(n0 + row) * (S_ * D_) + d0 + acol);
      short4_t v;
      v.x = f2bf(xv.x - mv.x); v.y = f2bf(xv.y - mv.y);
      v.z = f2bf(xv.z - mv.z); v.w = f2bf(xv.w - mv.w);
      *(short4_t*)&As[row][acol] = v;
    }
#pragma unroll
    for (int rr = 0; rr < 4; ++rr) {
      int row = brow + rr * 32;
      short8 v = *(const short8*)(bb + (size_t)row * D_ + d0 + bcol);
      *(short8*)&Bs[row][bcol] = v;
    }
    __syncthreads();
#pragma unroll
    for (int kk = 0; kk < 2; ++kk) {
      short8 af[4], bf[4];
#pragma unroll
      for (int i = 0; i < 4; ++i)
        af[i] = *(const short8*)&As[wr * 64 + i * 16 + lm][kk * 32 + quad * 8];
#pragma unroll
      for (int j = 0; j < 4; ++j)
        bf[j] = *(const short8*)&Bs[wc * 64 + j * 16 + lm][kk * 32 + quad * 8];
#pragma unroll
      for (int i = 0; i < 4; ++i)
#pragma unroll
        for (int j = 0; j < 4; ++j)
          acc[i][j] = __builtin_amdgcn_mfma_f32_16x16x32_bf16(
              af[i], bf[j], acc[i][j], 0, 0, 0);
    }
    __syncthreads();
  }

  // C/D layout: col = lane&15, row = quad*4 + reg  (verified m89/m91)
#pragma unroll
  for (int i = 0; i < 4; ++i) {
    int row = n0 + wr * 64 + i * 16 + quad * 4;
#pragma unroll
    for (int j = 0; j < 4; ++j) {
      int col = r * K_ + wc * 64 + j * 16 + lm;
#pragma unroll
      for (int g = 0; g < 4; ++g)
        coeffs[(size_t)(row + g) * (R_ * K_) + col] = f2bf(acc[i][j][g]);
    }
  }
}

// ---------------------------------------------------------------------------
// Pass 2 (MFMA): out(n,d) += coeffs(N x 12288)_bf16 . ibt(768 x 12288)_bf16^T
// Same tile structure; split-K over blockIdx.z; fp32 atomicAdd epilogue.
// Staging (round-3 bugfix): 4 rounds x 32 rows covers 128 rows x 64 shorts
// for BOTH As and Bs.
// ---------------------------------------------------------------------------
static constexpr int SPLITK = 8;
static constexpr int KC = R_ * K_ / SPLITK;  // 1536

__global__ __launch_bounds__(256) void k2_mfma(
    const short* __restrict__ coeffs, const short* __restrict__ ibt,
    float* __restrict__ out) {
  const int n0  = blockIdx.x * 128;
  const int dd0 = blockIdx.y * 128;
  const int kc0 = blockIdx.z * KC;
  const int ldk = R_ * K_;  // 12288

  __shared__ short As[128][72];
  __shared__ short Bs[128][72];

  const int t = threadIdx.x;
  const int wid = t >> 6, l = t & 63;
  const int wr = wid >> 1, wc = wid & 1;
  const int lm = l & 15, quad = l >> 4;

  floatx4 acc[4][4];
#pragma unroll
  for (int i = 0; i < 4; ++i)
#pragma unroll
    for (int j = 0; j < 4; ++j) acc[i][j] = (floatx4)(0.0f);

  const int srow = t >> 3;        // 0..31
  const int scol = (t & 7) * 8;   // 0..56 shorts

  for (int k0 = kc0; k0 < kc0 + KC; k0 += 64) {
#pragma unroll
    for (int rr = 0; rr < 4; ++rr) {
      int row = srow + rr * 32;
      short8 a = *(const short8*)(coeffs + (size_t)(n0 + row) * ldk + k0 + scol);
      *(short8*)&As[row][scol] = a;
      short8 b = *(const short8*)(ibt + (size_t)(dd0 + row) * ldk + k0 + scol);
      *(short8*)&Bs[row][scol] = b;
    }
    __syncthreads();
#pragma unroll
    for (int kk = 0; kk < 2; ++kk) {
      short8 af[4], bf[4];
#pragma unroll
      for (int i = 0; i < 4; ++i)
        af[i] = *(const short8*)&As[wr * 64 + i * 16 + lm][kk * 32 + quad * 8];
#pragma unroll
      for (int j = 0; j < 4; ++j)
        bf[j] = *(const short8*)&Bs[wc * 64 + j * 16 + lm][kk * 32 + quad * 8];
#pragma unroll
      for (int i = 0; i < 4; ++i)
#pragma unroll
        for (int j = 0; j < 4; ++j)
          acc[i][j] = __builtin_amdgcn_mfma_f32_16x16x32_bf16(
              af[i], bf[j], acc[i][j], 0, 0, 0);
    }
    __syncthreads();
  }

#pragma unroll
  for (int i = 0; i < 4; ++i) {
    int row = n0 + wr * 64 + i * 16 + quad * 4;
#pragma unroll
    for (int j = 0; j < 4; ++j) {
      int col = dd0 + wc * 64 + j * 16 + lm;
#pragma unroll
      for (int g = 0; g < 4; ++g)
        atomicAdd(&out[(size_t)(row + g) * D_ + col], acc[i][j][g]);
    }
  }
}

// ===========================================================================
// fp32 fallback path (verified round 2) — used only if ws_size is too small.
// ===========================================================================
__global__ __launch_bounds__(256) void k_pass1(
    const float* __restrict__ x, const float* __restrict__ bases,
    const float* __restrict__ means, const int* __restrict__ resi,
    const float* __restrict__ ul, float* __restrict__ coeffs,
    int r0, int Rc) {
  const int rz = blockIdx.z;
  const int r  = r0 + rz;
  const int n0 = blockIdx.x * 64;
  const int k0 = blockIdx.y * 64;
  const int s  = resi[r];
  __shared__ float As[64][33];
  __shared__ float Bs[64][33];
  const int t  = threadIdx.x;
  const int tx = t & 15, ty = t >> 4;
  const int lc = (t & 7) * 4;
  const int lr = t >> 3;
  const float* xbase = x + (size_t)s * D_;
  const float* bbase = bases + ((size_t)r * K_ + k0) * D_;
  const float* mbase = means + (size_t)r * D_;
  float acc[4][4] = {};
  for (int d0 = 0; d0 < D_; d0 += 32) {
    float4 mv = *(const float4*)(mbase + d0 + lc);
#pragma unroll
    for (int rr = 0; rr < 2; ++rr) {
      int row = lr + rr * 32;
      float4 xv = *(const float4*)(xbase + (size_t)(n0 + row) * (S_ * D_) + d0 + lc);
      As[row][lc + 0] = xv.x - mv.x; As[row][lc + 1] = xv.y - mv.y;
      As[row][lc + 2] = xv.z - mv.z; As[row][lc + 3] = xv.w - mv.w;
      float4 bv = *(const float4*)(bbase + (size_t)row * D_ + d0 + lc);
      Bs[row][lc + 0] = bv.x; Bs[row][lc + 1] = bv.y;
      Bs[row][lc + 2] = bv.z; Bs[row][lc + 3] = bv.w;
    }
    __syncthreads();
#pragma unroll
    for (int dd = 0; dd < 32; ++dd) {
      float a[4], b[4];
#pragma unroll
      for (int i = 0; i < 4; ++i) a[i] = As[ty * 4 + i][dd];
#pragma unroll
      for (int j = 0; j < 4; ++j) b[j] = Bs[tx * 4 + j][dd];
#pragma unroll
      for (int i = 0; i < 4; ++i)
#pragma unroll
        for (int j = 0; j < 4; ++j) acc[i][j] = fmaf(a[i], b[j], acc[i][j]);
    }
    __syncthreads();
  }
  const int ldc = Rc * K_;
#pragma unroll
  for (int i = 0; i < 4; ++i) {
    int n = n0 + ty * 4 + i;
#pragma unroll
    for (int j = 0; j < 4; ++j) {
      int k = k0 + tx * 4 + j;
      coeffs[(size_t)n * ldc + rz * K_ + k] = ul[r * K_ + k] * acc[i][j];
    }
  }
}

__global__ __launch_bounds__(256) void k_pass2(
    const float* __restrict__ coeffs, const float* __restrict__ invb,
    float* __restrict__ out, int Kg) {
  const int n0 = blockIdx.x * 64;
  const int d0 = blockIdx.y * 64;
  __shared__ float As[64][33];
  __shared__ float Bs[32][65];
  const int t  = threadIdx.x;
  const int tx = t & 15, ty = t >> 4;
  const int lca = (t & 7) * 4;
  const int lra = t >> 3;
  const int lcb = (t & 15) * 4;
  const int lrb = t >> 4;
  float acc[4][4] = {};
  for (int kk0 = 0; kk0 < Kg; kk0 += 32) {
#pragma unroll
    for (int rr = 0; rr < 2; ++rr) {
      int row = lra + rr * 32;
      float4 av = *(const float4*)(coeffs + (size_t)(n0 + row) * Kg + kk0 + lca);
      As[row][lca + 0] = av.x; As[row][lca + 1] = av.y;
      As[row][lca + 2] = av.z; As[row][lca + 3] = av.w;
      int brow = lrb + rr * 16;
      float4 bv = *(const float4*)(invb + (size_t)(kk0 + brow) * D_ + d0 + lcb);
      Bs[brow][lcb + 0] = bv.x; Bs[brow][lcb + 1] = bv.y;
      Bs[brow][lcb + 2] = bv.z; Bs[brow][lcb + 3] = bv.w;
    }
    __syncthreads();
#pragma unroll
    for (int kk = 0; kk < 32; ++kk) {
      float a[4], b[4];
#pragma unroll
      for (int i = 0; i < 4; ++i) a[i] = As[ty * 4 + i][kk];
#pragma unroll
      for (int j = 0; j < 4; ++j) b[j] = Bs[kk][tx * 4 + j];
#pragma unroll
      for (int i = 0; i < 4; ++i)
#pragma unroll
        for (int j = 0; j < 4; ++j) acc[i][j] = fmaf(a[i], b[j], acc[i][j]);
    }
    __syncthreads();
  }
#pragma unroll
  for (int i = 0; i < 4; ++i) {
    int n = n0 + ty * 4 + i;
#pragma unroll
    for (int j = 0; j < 4; ++j) {
      int d = d0 + tx * 4 + j;
      out[(size_t)n * D_ + d] += acc[i][j];
    }
  }
}

__global__ __launch_bounds__(256) void k_fused(
    const float* __restrict__ x, const float* __restrict__ bases,
    const float* __restrict__ invb, const float* __restrict__ means,
    const int* __restrict__ resi, const float* __restrict__ lambdas,
    const int* __restrict__ lens, float* __restrict__ out) {
  const int r  = blockIdx.y;
  const int n0 = blockIdx.x * 64;
  const int s  = resi[r];
  __shared__ float As[64][33];
  __shared__ float Bs[128][33];
  __shared__ float Cs[64][132];
  __shared__ float lam[K_];
  __shared__ int offS;
  const int t  = threadIdx.x;
  if (t == 0) {
    int o = 0;
    for (int i = 0; i < r; ++i) o += lens[i];
    offS = o;
  }
  __syncthreads();
  if (t < K_) lam[t] = (t < lens[r]) ? lambdas[offS + t] : 0.0f;
  const int lc = (t & 7) * 4;
  const int lr = t >> 3;
  const float* mbase = means + (size_t)r * D_;
  const float* bbase = bases + (size_t)r * K_ * D_;
  const int tx = t & 15, ty = t >> 4;
  float acc[4][8] = {};
  for (int d0 = 0; d0 < D_; d0 += 32) {
    float4 mv = *(const float4*)(mbase + d0 + lc);
#pragma unroll
    for (int rr = 0; rr < 2; ++rr) {
      int row = lr + rr * 32;
      float4 xv = *(const float4*)(x + ((size_t)(n0 + row) * S_ + s) * D_ + d0 + lc);
      As[row][lc + 0] = xv.x - mv.x; As[row][lc + 1] = xv.y - mv.y;
      As[row][lc + 2] = xv.z - mv.z; As[row][lc + 3] = xv.w - mv.w;
    }
#pragma unroll
    for (int rr = 0; rr < 4; ++rr) {
      int row = lr + rr * 32;
      float4 bv = *(const float4*)(bbase + (size_t)row * D_ + d0 + lc);
      Bs[row][lc + 0] = bv.x; Bs[row][lc + 1] = bv.y;
      Bs[row][lc + 2] = bv.z; Bs[row][lc + 3] = bv.w;
    }
    __syncthreads();
#pragma unroll
    for (int dd = 0; dd < 32; ++dd) {
      float a[4], b[8];
#pragma unroll
      for (int i = 0; i < 4; ++i) a[i] = As[ty * 4 + i][dd];
#pragma unroll
      for (int j = 0; j < 8; ++j) b[j] = Bs[tx * 8 + j][dd];
#pragma unroll
      for (int i = 0; i < 4; ++i)
#pragma unroll
        for (int j = 0; j < 8; ++j) acc[i][j] = fmaf(a[i], b[j], acc[i][j]);
    }
    __syncthreads();
  }
#pragma unroll
  for (int i = 0; i < 4; ++i)
#pragma unroll
    for (int j = 0; j < 8; ++j)
      Cs[ty * 4 + i][tx * 8 + j] = lam[tx * 8 + j] * acc[i][j];
  __syncthreads();
  const float* ibase = invb + (size_t)r * K_ * D_;
  const int tx2 = t & 15;
  for (int d0 = 0; d0 < D_; d0 += 32) {
#pragma unroll
    for (int rr = 0; rr < 4; ++rr) {
      int row = lr + rr * 32;
      float4 bv = *(const float4*)(ibase + (size_t)row * D_ + d0 + lc);
      Bs[row][lc + 0] = bv.x; Bs[row][lc + 1] = bv.y;
      Bs[row][lc + 2] = bv.z; Bs[row][lc + 3] = bv.w;
    }
    __syncthreads();
    float c[4][2] = {};
#pragma unroll
    for (int k = 0; k < K_; ++k) {
      float a[4], b[2];
#pragma unroll
      for (int i = 0; i < 4; ++i) a[i] = Cs[ty * 4 + i][k];
#pragma unroll
      for (int j = 0; j < 2; ++j) b[j] = Bs[k][tx2 * 2 + j];
#pragma unroll
      for (int i = 0; i < 4; ++i)
#pragma unroll
        for (int j = 0; j < 2; ++j) c[i][j] = fmaf(a[i], b[j], c[i][j]);
    }
#pragma unroll
    for (int i = 0; i < 4; ++i)
#pragma unroll
      for (int j = 0; j < 2; ++j)
        atomicAdd(&out[(size_t)(n0 + ty * 4 + i) * D_ + d0 + tx2 * 2 + j], c[i][j]);
    __syncthreads();
  }
}

// ---------------------------------------------------------------------------
extern "C" void kernel_launch(void* const* d_in, const int* in_sizes, int n_in,
                              void* d_out, int out_size, void* d_ws, size_t ws_size,
                              hipStream_t stream) {
  const float* x       = (const float*)d_in[0];
  const float* lambdas = (const float*)d_in[1];
  const float* bases   = (const float*)d_in[2];
  const float* invb    = (const float*)d_in[3];
  const float* means   = (const float*)d_in[4];
  const int*   resi    = (const int*)d_in[5];
  const int*   abl     = (const int*)d_in[6];
  const int*   lens    = (const int*)d_in[7];
  float* out = (float*)d_out;
  const int nab = in_sizes[6];

  // ws layout for MFMA path:
  //   ul     (R*K fp32)         48 KB
  //   bbf    (R*K*D bf16)     18.87 MB   bases * lambda
  //   ibt    (D x R*K bf16)   18.87 MB   invb transposed
  //   coeffs (N x R*K bf16)   25.17 MB
  const size_t ul_b  = (size_t)R_ * K_ * sizeof(float);
  const size_t bbf_b = (size_t)R_ * K_ * D_ * sizeof(short);
  const size_t ibt_b = (size_t)D_ * R_ * K_ * sizeof(short);
  const size_t cf_b  = (size_t)N_ * R_ * K_ * sizeof(short);
  const size_t need  = ul_b + bbf_b + ibt_b + cf_b;

  k_ablated<<<(N_ * D_ / 4 + 255) / 256, 256, 0, stream>>>(x, abl, out, nab);

  if (ws_size >= need) {
    float* ul   = (float*)d_ws;
    short* bbf  = (short*)((char*)d_ws + ul_b);
    short* ibt  = (short*)((char*)d_ws + ul_b + bbf_b);
    short* cfs  = (short*)((char*)d_ws + ul_b + bbf_b + ibt_b);

    k_pad_lambdas<<<1, 256, 0, stream>>>(lambdas, lens, ul);
    k_cvt_bases<<<(R_ * K_ * D_ / 4 + 255) / 256, 256, 0, stream>>>(bases, ul, bbf);
    dim3 gt(D_ / 32, K_ / 32, R_);
    k_trans_inv<<<gt, 256, 0, stream>>>(invb, ibt);
    dim3 g1(N_ / 128, R_);
    k1_mfma<<<g1, 256, 0, stream>>>(x, bbf, means, resi, cfs);
    dim3 g2(N_ / 128, D_ / 128, SPLITK);
    k2_mfma<<<g2, 256, 0, stream>>>(cfs, ibt, out);
    return;
  }

  // fp32 fallback
  const size_t per_r = (size_t)N_ * K_ * sizeof(float);
  if (ws_size >= ul_b + per_r) {
    float* ul = (float*)d_ws;
    float* coeffs = (float*)((char*)d_ws + ul_b);
    int Rc = (int)((ws_size - ul_b) / per_r);
    if (Rc > R_) Rc = R_;
    k_pad_lambdas<<<1, 256, 0, stream>>>(lambdas, lens, ul);
    for (int r0 = 0; r0 < R_; r0 += Rc) {
      int rc = (R_ - r0 < Rc) ? (R_ - r0) : Rc;
      dim3 g1(N_ / 64, K_ / 64, rc);
      k_pass1<<<g1, 256, 0, stream>>>(x, bases, means, resi, ul, coeffs, r0, rc);
      dim3 g2(N_ / 64, D_ / 64);
      k_pass2<<<g2, 256, 0, stream>>>(coeffs, invb + (size_t)r0 * K_ * D_, out,
                                      rc * K_);
    }
  } else {
    dim3 g(N_ / 64, R_);
    k_fused<<<g, 256, 0, stream>>>(x, bases, invb, means, resi, lambdas, lens,
                                   out);
  }
}